// Round 9
// baseline (155.849 us; speedup 1.0000x reference)
//
#include <hip/hip_runtime.h>

// B=16 images, A=65536 anchors, G=32 gts. Inputs float32; output slot read as
// bf16 low-16-bits (dual-encode store gives absmax 0.0 -> keep it).
#define BB 16
#define AA 65536
#define GG 32
// Histogram: key = (float_bits>>14) - KOFF, bin 0 == 2^-10, 512 bins/octave.
// Count-only, value = bin midpoint (rel err <= 2^-10 << 2% budget).
#define NB 8192
#define KOFF 59904u          // __float_as_uint(2^-10) >> 14
#define AT 8                 // anchors per thread in k_matchforce (R9: 4 -> 8)
#define APB (256 * AT)       // 2048 anchors per block
#define MBLK (AA / APB)      // 32 match blocks per image
#define NSEG 64              // stats segments per image (4 blk/CU occupancy)
#define SEGA (AA / NSEG)     // 1024 anchors per stats block

// Static scratch: fully rewritten every call before any read. Re-poison safe.
// R9: histogram PARTIALS are gone (R8 post-mortem: 16 MB write + 16 MB
// 16-CU fold was the dominant controllable cost; the per-block hist was
// >99% zeros). k_stats now emits its <=1024 negative bin-keys COMPACTLY
// (u16, 2 KB/block max); k_select histograms them directly. Slot order from
// the LDS counter is nondeterministic but the key MULTISET is deterministic
// and a histogram is order-invariant -> bit-exact.
__device__ unsigned char  g_mask[(size_t)BB * AA];
__device__ unsigned char  g_bidx[(size_t)BB * AA];
__device__ unsigned short g_nkey[(size_t)BB * NSEG * SEGA];   // 2 MB compact keys
__device__ int   g_ncnt[BB * NSEG];
__device__ float g_spart[BB * NSEG * 2];   // pos, loc partials
__device__ int   g_npart[BB * NSEG];
__device__ float g_loc[BB], g_pos[BB], g_neg[BB];
__device__ int   g_npos[BB], g_nneg[BB];

// Dynamic scratch, zeroed by ONE small hipMemsetAsync (4 KB) each call:
// [0, BB*GG*2)  u64 per-(b,g) force-match keys (global atomicMax)
// [+2]          done counter for the last-block final combine
#define DYN_U32 (BB * GG * 2 + 2)
__device__ unsigned int g_dyn[DYN_U32];
__device__ __forceinline__ unsigned long long* fkeyp() {
    return (unsigned long long*)g_dyn;               // 8-aligned
}
__device__ __forceinline__ int* donep() {
    return (int*)(g_dyn + BB * GG * 2);
}

__device__ __forceinline__ float midval(int bin) {
    return __uint_as_float((((unsigned int)bin + KOFF) << 14) | 8192u);
}

// ---------------------------------------------------------------------------
// Kernel 1: fused per-anchor match + per-gt force-match.
// grid (MBLK, B), block 256, AT=8 anchors/thread (strided, coalesced) --
// amortizes the per-gt butterfly 2x over R8's AT=4. Spill tripwire:
// WRITE_SIZE inflation (R3 signature); est ~100 VGPR < 128 cap.
// Divide-free scoring: r = inter/(areaA+areaG), monotone in IoU (iou=r/(1-r)),
// argmax-equivalent; iou>0.5 <=> r>1/3. rcp 1-ulp absorbed by bf16 budget
// (R2-R8 benches: absmax 0.0).
// Reduction (R6-proven): per gt, thread reduces its AT candidates in registers
// to key=(r_bits<<32)|(~offset) (tie-break = lowest offset, exact), 6-level
// __shfl_xor u64 butterfly, lane0 -> wkey[wave][g]; after barrier t<32 folds
// the 4 wave partials and fires ONE global atomicMax into fkey[b][g] with the
// GLOBAL anchor id in the low word (32 blocks/image x 32 keys: negligible).
__global__ void __launch_bounds__(256, 4)
k_matchforce(const float4* __restrict__ anchors,
             const float4* __restrict__ gts) {
    __shared__ float4 sg[GG];
    __shared__ unsigned long long wkey[4][GG];
    const int b = blockIdx.y;
    const int t = threadIdx.x;
    const int wave = t >> 6, lane = t & 63;
    if (t < GG) sg[t] = gts[(size_t)b * GG + t];
    __syncthreads();

    const size_t abase = (size_t)b * AA + (size_t)blockIdx.x * APB;

    float ax0[AT], ay0[AT], ax1[AT], ay1[AT], aar[AT], best[AT];
    int bg[AT];
#pragma unroll
    for (int j = 0; j < AT; ++j) {
        const float4 av = anchors[abase + j * 256 + t];
        ax0[j] = av.x; ay0[j] = av.y; ax1[j] = av.z; ay1[j] = av.w;
        aar[j] = (av.z - av.x) * (av.w - av.y);
        best[j] = -1.0f; bg[j] = 0;
    }

#pragma unroll 2
    for (int g = 0; g < GG; ++g) {
        const float4 gb = sg[g];
        const float ga = (gb.z - gb.x) * (gb.w - gb.y);
        float fbest = -1.0f;              // r >= 0 always -> j=0 wins init
        int fo = t;                       // block-local offset of j=0 anchor
#pragma unroll
        for (int j = 0; j < AT; ++j) {
            const float lx = fmaxf(ax0[j], gb.x), ly = fmaxf(ay0[j], gb.y);
            const float rx = fminf(ax1[j], gb.z), ry = fminf(ay1[j], gb.w);
            const float w = fmaxf(rx - lx, 0.0f), h = fmaxf(ry - ly, 0.0f);
            const float inter = w * h;
            const float s = aar[j] + ga;                    // areaA + areaG > 0
            const float r = inter * __builtin_amdgcn_rcpf(s);
            if (r > best[j]) { best[j] = r; bg[j] = g; }    // strict >: first max
            if (r > fbest)   { fbest = r; fo = j * 256 + t; }
        }
        // packed key: fbest >= 0 so float bits are unsigned-monotone; low word
        // = ~offset so larger key == smaller anchor offset on value ties.
        unsigned long long key =
            ((unsigned long long)__float_as_uint(fbest) << 32) |
            (unsigned long long)(0xFFFFFFFFu - (unsigned int)fo);
#pragma unroll
        for (int off = 1; off < 64; off <<= 1) {
            const unsigned long long o = __shfl_xor(key, off, 64);
            if (o > key) key = o;
        }
        if (lane == 0) wkey[wave][g] = key;
    }

#pragma unroll
    for (int j = 0; j < AT; ++j) {
        g_mask[abase + j * 256 + t] = (best[j] > (1.0f / 3.0f)) ? 1 : 0;
        g_bidx[abase + j * 256 + t] = (unsigned char)bg[j];
    }
    __syncthreads();
    if (t < GG) {
        unsigned long long k = wkey[0][t];
#pragma unroll
        for (int w = 1; w < 4; ++w) {
            const unsigned long long k1 = wkey[w][t];
            if (k1 > k) k = k1;
        }
        // re-pack low word with the GLOBAL anchor id; fire one device atomic.
        const unsigned int off = 0xFFFFFFFFu - (unsigned int)(k & 0xFFFFFFFFull);
        const unsigned int ga = (unsigned int)(blockIdx.x * APB) + off;
        atomicMax(&fkeyp()[b * GG + t],
                  (k & 0xFFFFFFFF00000000ull) |
                  (unsigned long long)(0xFFFFFFFFu - ga));
    }
}

// ---------------------------------------------------------------------------
// Kernel 2: segmented per-image stats. grid (NSEG=64, B), block 256
// (1024 blocks, 4/CU).
// Forced positives: read the 32 folded fkeys (256 B), mark in-segment winners
// in a 128 B LDS bitmap. Positive = g_mask OR bitmap bit.
// Negatives: bin-key computed and COMPACTED into LDS u16 buffer (slot via one
// LDS atomicAdd per thread with >=1 neg); <=2 KB streamed out per block.
// No LDS hist, no 16 KB init/writeout (R8 lesson), no global atomics (R7).
__global__ void k_stats(const float4* __restrict__ bbox,
                        const float* __restrict__ conf,
                        const float4* __restrict__ gts) {
    __shared__ float4 sg[GG];
    __shared__ unsigned int bmap[SEGA / 32];  // 128 B forced-positive bitmap
    __shared__ unsigned short nk[SEGA];       // 2 KB compact negative keys
    __shared__ unsigned int ncnt;
    __shared__ float rf[256], rf2[256];
    __shared__ unsigned int ru[256];
    const int b = blockIdx.y, seg = blockIdx.x, t = threadIdx.x;
    if (t < GG) sg[t] = gts[(size_t)b * GG + t];
    if (t < SEGA / 32) bmap[t] = 0u;
    if (t == 0) ncnt = 0u;
    __syncthreads();
    if (t < GG) {
        const unsigned long long k = fkeyp()[b * GG + t];
        const unsigned int a = 0xFFFFFFFFu - (unsigned int)(k & 0xFFFFFFFFull);
        const int la = (int)a - seg * SEGA;
        if (la >= 0 && la < SEGA) atomicOr(&bmap[la >> 5], 1u << (la & 31));
    }
    __syncthreads();

    const size_t base = (size_t)b * AA + (size_t)seg * SEGA;   // anchor units
    const float4* c4 = (const float4*)(conf + base);
    const uchar4* m4 = (const uchar4*)(g_mask + base);
    const uchar4* x4 = (const uchar4*)(g_bidx + base);
    const float4* bb4 = bbox + base;

    float pos = 0.0f, loc = 0.0f;
    int np = 0;
    {
        const int idx = t;                     // 4 consecutive anchors/thread
        const float4 p4 = c4[idx];
        const uchar4 mm = m4[idx];
        const uchar4 xx = x4[idx];
        const unsigned int bw = (bmap[idx >> 3] >> ((idx & 7) * 4)) & 0xFu;
        const float pv[4] = {p4.x, p4.y, p4.z, p4.w};
        const unsigned char mv[4] = {mm.x, mm.y, mm.z, mm.w};
        const unsigned char xv[4] = {xx.x, xx.y, xx.z, xx.w};
        unsigned short lk[4];                  // this thread's negative keys
        int ln = 0;
#pragma unroll
        for (int c = 0; c < 4; ++c) {
            const float p = pv[c];
            if (mv[c] | ((bw >> c) & 1u)) {
                np += 1;
                pos += -logf(p);
                const float4 bv = bb4[4 * idx + c];
                const float4 gb = sg[xv[c]];
                const float d0 = (bv.x + bv.z) * 0.5f - (gb.x + gb.z) * 0.5f;
                const float d1 = (bv.y + bv.w) * 0.5f - (gb.y + gb.w) * 0.5f;
                const float d2 = (bv.z - bv.x) - (gb.z - gb.x);
                const float d3 = (bv.w - bv.y) - (gb.w - gb.y);
                float ds[4] = {d0, d1, d2, d3};
#pragma unroll
                for (int q = 0; q < 4; ++q) {
                    float ax = fabsf(ds[q]);
                    loc += (ax < 1.0f) ? 0.5f * ax * ax : ax - 0.5f;
                }
            } else {
                const float nb = -log1pf(-p);
                int key = (int)(__float_as_uint(nb) >> 14) - (int)KOFF;
                key = key < 0 ? 0 : (key > NB - 1 ? NB - 1 : key);
                lk[ln++] = (unsigned short)key;
            }
        }
        if (ln) {
            const unsigned int slot = atomicAdd(&ncnt, (unsigned int)ln);
            for (int i = 0; i < ln; ++i) nk[slot + i] = lk[i];
        }
    }
    // block reduce np/pos/loc; barriers also fence nk/ncnt
    ru[t] = (unsigned int)np; rf[t] = pos; rf2[t] = loc;
    __syncthreads();
    // pad to even with sentinel so k_select can read u32 pairs (cnt odd =>
    // cnt <= 1023, so nk[cnt] is in bounds)
    if (t == 0 && (ncnt & 1u)) nk[ncnt] = 0xFFFFu;
    for (int w = 128; w > 0; w >>= 1) {
        if (t < w) { ru[t] += ru[t + w]; rf[t] += rf[t + w]; rf2[t] += rf2[t + w]; }
        __syncthreads();
    }
    if (t == 0) {
        g_npart[b * NSEG + seg] = (int)ru[0];
        g_spart[(b * NSEG + seg) * 2 + 0] = rf[0];
        g_spart[(b * NSEG + seg) * 2 + 1] = rf2[0];
        g_ncnt[b * NSEG + seg] = (int)ncnt;
    }
    // coalesced u32 writeout of the compact keys (ceil(cnt/2) words)
    const unsigned int cw = (ncnt + 1u) >> 1;
    const unsigned int* nk32 = (const unsigned int*)nk;
    unsigned int* outk = (unsigned int*)(g_nkey + ((size_t)b * NSEG + seg) * SEGA);
    for (unsigned int j = t; j < cw; j += 256) outk[j] = nk32[j];
}

// ---------------------------------------------------------------------------
// Kernel 3: per-image hist build + hard-negative top-k + final combine.
// grid B, block 1024. Reads ~64 x <=2 KB compact key lists (~128 KB/image),
// histograms them straight into LDS u32 (hot bin ~23 -> negligible conflict),
// then the R6-proven scan. Seg partials folded wave-parallel (t<64 + shfl).
// Cross-block handoff: __threadfence + done counter; 16th block agent-scope
// loads and writes the dual-bf16-encoded output.
__global__ void __launch_bounds__(1024) k_select(unsigned int* __restrict__ out) {
    __shared__ unsigned int hist[NB];         // 32 KB
    __shared__ unsigned int ru[1024];
    __shared__ unsigned int s2[32];
    __shared__ int scnt[NSEG];
    __shared__ float sh_pos, sh_loc;
    __shared__ int sh_np, sh_k, sh_bsel;
    __shared__ unsigned int sh_take;
    __shared__ float rf[1024];

    const int b = blockIdx.x, t = threadIdx.x;
    for (int j = t; j < NB; j += 1024) hist[j] = 0u;
    if (t < NSEG) scnt[t] = g_ncnt[b * NSEG + t];
    if (t < 64) {                             // wave-parallel seg-partial fold
        int np = g_npart[b * NSEG + t];
        float pos = g_spart[(b * NSEG + t) * 2 + 0];
        float loc = g_spart[(b * NSEG + t) * 2 + 1];
#pragma unroll
        for (int off = 32; off > 0; off >>= 1) {
            np  += __shfl_xor(np,  off, 64);
            pos += __shfl_xor(pos, off, 64);
            loc += __shfl_xor(loc, off, 64);
        }
        if (t == 0) { sh_np = np; sh_pos = pos; sh_loc = loc; }
    }
    __syncthreads();
    // histogram the compact keys (order-invariant -> deterministic)
    for (int s = 0; s < NSEG; ++s) {
        const unsigned int cnt = (unsigned int)scnt[s];
        const unsigned int cw = (cnt + 1u) >> 1;
        const unsigned int* kp =
            (const unsigned int*)(g_nkey + ((size_t)b * NSEG + s) * SEGA);
        for (unsigned int j = t; j < cw; j += 1024) {
            const unsigned int v = kp[j];
            atomicAdd(&hist[v & 0xFFFFu], 1u);              // lo always valid
            const unsigned int k1 = v >> 16;
            if (k1 != 0xFFFFu) atomicAdd(&hist[k1], 1u);    // hi unless pad
        }
    }
    __syncthreads();
    const int np_tot = sh_np;

    // descending chunk counts: thread t covers bins NB-1-8t .. NB-8-8t
    unsigned int c = 0;
    const int hi = NB - 1 - t * 8;
#pragma unroll
    for (int j = 0; j < 8; ++j) c += hist[hi - j];
    ru[t] = c;
    __syncthreads();
    if (t < 32) {
        unsigned int x = 0;
#pragma unroll
        for (int j = 0; j < 32; ++j) x += ru[t * 32 + j];
        s2[t] = x;
    }
    __syncthreads();
    if (t == 0) {
        int k = 3 * np_tot;
        const int maxneg = AA - np_tot;
        if (k > maxneg) k = maxneg;
        sh_k = k;
        int bsel = NB;            // NB => nothing selected
        unsigned int take = 0;
        if (k > 0) {
            unsigned int cum = 0;
            int u = 0;
            while (u < 31 && cum + s2[u] < (unsigned int)k) { cum += s2[u]; ++u; }
            int cc = u * 32;
            while (cc < 1023 && cum + ru[cc] < (unsigned int)k) { cum += ru[cc]; ++cc; }
            const int h2 = NB - 1 - cc * 8;
            int j = 0;
            while (j < 7 && cum + hist[h2 - j] < (unsigned int)k) { cum += hist[h2 - j]; ++j; }
            bsel = h2 - j;
            take = (unsigned int)k - cum;
        }
        sh_bsel = bsel; sh_take = take;
    }
    __syncthreads();
    const int bsel = sh_bsel;
    float negp = 0.0f;
    for (int j = t; j < NB; j += 1024)
        if (j > bsel) { unsigned int cnt = hist[j]; if (cnt) negp += (float)cnt * midval(j); }
    rf[t] = negp;
    __syncthreads();
    for (int w = 512; w > 0; w >>= 1) {
        if (t < w) rf[t] += rf[t + w];
        __syncthreads();
    }
    if (t == 0) {
        float neg = 0.0f;
        if (sh_k > 0) neg = rf[0] + (float)sh_take * midval(bsel < NB ? bsel : 0);
        g_loc[b] = sh_loc; g_pos[b] = sh_pos; g_neg[b] = neg;
        g_npos[b] = np_tot; g_nneg[b] = sh_k;

        __threadfence();                        // publish before counting in
        const int old = atomicAdd(donep(), 1);
        if (old == BB - 1) {                    // last image: final combine
            __threadfence();
            float loc = 0.0f, conf = 0.0f;
            int tot = 0;
            for (int bb = 0; bb < BB; ++bb) {
                const float lv = __hip_atomic_load(&g_loc[bb],  __ATOMIC_RELAXED, __HIP_MEMORY_SCOPE_AGENT);
                const float pv = __hip_atomic_load(&g_pos[bb],  __ATOMIC_RELAXED, __HIP_MEMORY_SCOPE_AGENT);
                const float nv = __hip_atomic_load(&g_neg[bb],  __ATOMIC_RELAXED, __HIP_MEMORY_SCOPE_AGENT);
                const int   np = __hip_atomic_load(&g_npos[bb], __ATOMIC_RELAXED, __HIP_MEMORY_SCOPE_AGENT);
                const int   nn = __hip_atomic_load(&g_nneg[bb], __ATOMIC_RELAXED, __HIP_MEMORY_SCOPE_AGENT);
                loc += lv;
                conf += pv / (float)(np > 1 ? np : 1) +
                        nv / (float)(nn > 1 ? nn : 1);
                tot += np;
            }
            const float total = loc / (float)(tot > 1 ? tot : 1) + conf / (float)BB;
            const unsigned int u = __float_as_uint(total);
            const unsigned int r = 0x7FFFu + ((u >> 16) & 1u);
            const unsigned int bf = (u + r) >> 16;      // bf16(total), RNE
            out[0] = (bf << 16) | bf;
        }
    }
}

extern "C" void kernel_launch(void* const* d_in, const int* in_sizes, int n_in,
                              void* d_out, int out_size, void* d_ws, size_t ws_size,
                              hipStream_t stream) {
    const float4* bbox    = (const float4*)d_in[0];
    const float*  conf    = (const float*)d_in[1];
    const float4* anchors = (const float4*)d_in[2];
    const float4* gts     = (const float4*)d_in[3];

    static unsigned int* dynp = nullptr;       // cached symbol address
    if (!dynp) hipGetSymbolAddress((void**)&dynp, HIP_SYMBOL(g_dyn));
    hipMemsetAsync(dynp, 0, sizeof(unsigned int) * DYN_U32, stream);

    k_matchforce<<<dim3(MBLK, BB), 256, 0, stream>>>(anchors, gts);
    k_stats<<<dim3(NSEG, BB), 256, 0, stream>>>(bbox, conf, gts);
    k_select<<<BB, 1024, 0, stream>>>((unsigned int*)d_out);
}

// Round 10
// 141.639 us; speedup vs baseline: 1.1003x; 1.1003x over previous
//
#include <hip/hip_runtime.h>

// B=16 images, A=65536 anchors, G=32 gts. Inputs float32; output slot read as
// bf16 low-16-bits (dual-encode store gives absmax 0.0 -> keep it).
#define BB 16
#define AA 65536
#define GG 32
// Histogram: key = (float_bits>>14) - KOFF, bin 0 == 2^-10, 512 bins/octave.
// Count-only, value = bin midpoint (rel err <= 2^-10 << 2% budget).
#define NB 8192
#define KOFF 59904u          // __float_as_uint(2^-10) >> 14
#define AT 4                 // anchors per thread (R10: revert 8 -> 4; 8 halved
                             // the grid to 2 blk/CU and regressed)
#define APB (256 * AT)       // 1024 anchors per block
#define MBLK (AA / APB)      // 64 match blocks per image
#define NSEG 64              // stats segments per image (4 blk/CU occupancy)
#define SEGA (AA / NSEG)     // 1024 anchors per stats block

// Static scratch: fully rewritten every call before any read. Re-poison safe.
// Compact-negative fabric (R9, kept): k_stats emits its <=1024 negative
// bin-keys compactly (u16, <=2 KB/block); k_select histograms them directly.
// Slot order from the LDS counter is nondeterministic but the key MULTISET is
// deterministic and a histogram is order-invariant -> bit-exact.
__device__ unsigned char  g_mask[(size_t)BB * AA];
__device__ unsigned char  g_bidx[(size_t)BB * AA];
__device__ unsigned short g_nkey[(size_t)BB * NSEG * SEGA];   // 2 MB compact keys
__device__ int   g_ncnt[BB * NSEG];
__device__ float g_spart[BB * NSEG * 2];   // pos, loc partials
__device__ int   g_npart[BB * NSEG];
__device__ float g_loc[BB], g_pos[BB], g_neg[BB];
__device__ int   g_npos[BB], g_nneg[BB];

// Dynamic scratch, zeroed by ONE small hipMemsetAsync (4 KB) each call:
// [0, BB*GG*2)  u64 per-(b,g) force-match keys (global atomicMax)
// [+2]          done counter for the last-block final combine
#define DYN_U32 (BB * GG * 2 + 2)
__device__ unsigned int g_dyn[DYN_U32];
__device__ __forceinline__ unsigned long long* fkeyp() {
    return (unsigned long long*)g_dyn;               // 8-aligned
}
__device__ __forceinline__ int* donep() {
    return (int*)(g_dyn + BB * GG * 2);
}

__device__ __forceinline__ float midval(int bin) {
    return __uint_as_float((((unsigned int)bin + KOFF) << 14) | 8192u);
}

// ---------------------------------------------------------------------------
// Kernel 1: fused per-anchor match + per-gt force-match.  (R8-proven config)
// grid (MBLK=64, B), block 256, AT=4 anchors/thread (strided, coalesced),
// 1024 blocks = 4 blk/CU.
// Divide-free scoring: r = inter/(areaA+areaG), monotone in IoU (iou=r/(1-r)),
// argmax-equivalent; iou>0.5 <=> r>1/3. rcp 1-ulp absorbed by bf16 budget
// (R2-R9 benches: absmax 0.0).
// Reduction (R6-proven): per gt, thread reduces its AT candidates in registers
// to key=(r_bits<<32)|(~offset) (tie-break = lowest offset, exact), 6-level
// __shfl_xor u64 butterfly, lane0 -> wkey[wave][g]; after barrier t<32 folds
// the 4 wave partials and fires ONE global atomicMax into fkey[b][g] with the
// GLOBAL anchor id in the low word (64 blocks/image x 32 keys: negligible).
__global__ void __launch_bounds__(256, 4)
k_matchforce(const float4* __restrict__ anchors,
             const float4* __restrict__ gts) {
    __shared__ float4 sg[GG];
    __shared__ unsigned long long wkey[4][GG];
    const int b = blockIdx.y;
    const int t = threadIdx.x;
    const int wave = t >> 6, lane = t & 63;
    if (t < GG) sg[t] = gts[(size_t)b * GG + t];
    __syncthreads();

    const size_t abase = (size_t)b * AA + (size_t)blockIdx.x * APB;

    float ax0[AT], ay0[AT], ax1[AT], ay1[AT], aar[AT], best[AT];
    int bg[AT];
#pragma unroll
    for (int j = 0; j < AT; ++j) {
        const float4 av = anchors[abase + j * 256 + t];
        ax0[j] = av.x; ay0[j] = av.y; ax1[j] = av.z; ay1[j] = av.w;
        aar[j] = (av.z - av.x) * (av.w - av.y);
        best[j] = -1.0f; bg[j] = 0;
    }

#pragma unroll 2
    for (int g = 0; g < GG; ++g) {
        const float4 gb = sg[g];
        const float ga = (gb.z - gb.x) * (gb.w - gb.y);
        float fbest = -1.0f;              // r >= 0 always -> j=0 wins init
        int fo = t;                       // block-local offset of j=0 anchor
#pragma unroll
        for (int j = 0; j < AT; ++j) {
            const float lx = fmaxf(ax0[j], gb.x), ly = fmaxf(ay0[j], gb.y);
            const float rx = fminf(ax1[j], gb.z), ry = fminf(ay1[j], gb.w);
            const float w = fmaxf(rx - lx, 0.0f), h = fmaxf(ry - ly, 0.0f);
            const float inter = w * h;
            const float s = aar[j] + ga;                    // areaA + areaG > 0
            const float r = inter * __builtin_amdgcn_rcpf(s);
            if (r > best[j]) { best[j] = r; bg[j] = g; }    // strict >: first max
            if (r > fbest)   { fbest = r; fo = j * 256 + t; }
        }
        // packed key: fbest >= 0 so float bits are unsigned-monotone; low word
        // = ~offset so larger key == smaller anchor offset on value ties.
        unsigned long long key =
            ((unsigned long long)__float_as_uint(fbest) << 32) |
            (unsigned long long)(0xFFFFFFFFu - (unsigned int)fo);
#pragma unroll
        for (int off = 1; off < 64; off <<= 1) {
            const unsigned long long o = __shfl_xor(key, off, 64);
            if (o > key) key = o;
        }
        if (lane == 0) wkey[wave][g] = key;
    }

#pragma unroll
    for (int j = 0; j < AT; ++j) {
        g_mask[abase + j * 256 + t] = (best[j] > (1.0f / 3.0f)) ? 1 : 0;
        g_bidx[abase + j * 256 + t] = (unsigned char)bg[j];
    }
    __syncthreads();
    if (t < GG) {
        unsigned long long k = wkey[0][t];
#pragma unroll
        for (int w = 1; w < 4; ++w) {
            const unsigned long long k1 = wkey[w][t];
            if (k1 > k) k = k1;
        }
        // re-pack low word with the GLOBAL anchor id; fire one device atomic.
        const unsigned int off = 0xFFFFFFFFu - (unsigned int)(k & 0xFFFFFFFFull);
        const unsigned int ga = (unsigned int)(blockIdx.x * APB) + off;
        atomicMax(&fkeyp()[b * GG + t],
                  (k & 0xFFFFFFFF00000000ull) |
                  (unsigned long long)(0xFFFFFFFFu - ga));
    }
}

// ---------------------------------------------------------------------------
// Kernel 2: segmented per-image stats. grid (NSEG=64, B), block 256
// (1024 blocks, 4/CU).
// Forced positives: read the 32 folded fkeys (256 B), mark in-segment winners
// in a 128 B LDS bitmap. Positive = g_mask OR bitmap bit.
// Negatives: bin-key computed and COMPACTED into LDS u16 buffer (slot via one
// LDS atomicAdd per thread with >=1 neg); <=2 KB streamed out per block.
// No LDS hist (R8 lesson), no global atomics on hot path (R7 lesson).
__global__ void k_stats(const float4* __restrict__ bbox,
                        const float* __restrict__ conf,
                        const float4* __restrict__ gts) {
    __shared__ float4 sg[GG];
    __shared__ unsigned int bmap[SEGA / 32];  // 128 B forced-positive bitmap
    __shared__ unsigned short nk[SEGA];       // 2 KB compact negative keys
    __shared__ unsigned int ncnt;
    __shared__ float rf[256], rf2[256];
    __shared__ unsigned int ru[256];
    const int b = blockIdx.y, seg = blockIdx.x, t = threadIdx.x;
    if (t < GG) sg[t] = gts[(size_t)b * GG + t];
    if (t < SEGA / 32) bmap[t] = 0u;
    if (t == 0) ncnt = 0u;
    __syncthreads();
    if (t < GG) {
        const unsigned long long k = fkeyp()[b * GG + t];
        const unsigned int a = 0xFFFFFFFFu - (unsigned int)(k & 0xFFFFFFFFull);
        const int la = (int)a - seg * SEGA;
        if (la >= 0 && la < SEGA) atomicOr(&bmap[la >> 5], 1u << (la & 31));
    }
    __syncthreads();

    const size_t base = (size_t)b * AA + (size_t)seg * SEGA;   // anchor units
    const float4* c4 = (const float4*)(conf + base);
    const uchar4* m4 = (const uchar4*)(g_mask + base);
    const uchar4* x4 = (const uchar4*)(g_bidx + base);
    const float4* bb4 = bbox + base;

    float pos = 0.0f, loc = 0.0f;
    int np = 0;
    {
        const int idx = t;                     // 4 consecutive anchors/thread
        const float4 p4 = c4[idx];
        const uchar4 mm = m4[idx];
        const uchar4 xx = x4[idx];
        const unsigned int bw = (bmap[idx >> 3] >> ((idx & 7) * 4)) & 0xFu;
        const float pv[4] = {p4.x, p4.y, p4.z, p4.w};
        const unsigned char mv[4] = {mm.x, mm.y, mm.z, mm.w};
        const unsigned char xv[4] = {xx.x, xx.y, xx.z, xx.w};
        unsigned short lk[4];                  // this thread's negative keys
        int ln = 0;
#pragma unroll
        for (int c = 0; c < 4; ++c) {
            const float p = pv[c];
            if (mv[c] | ((bw >> c) & 1u)) {
                np += 1;
                pos += -logf(p);
                const float4 bv = bb4[4 * idx + c];
                const float4 gb = sg[xv[c]];
                const float d0 = (bv.x + bv.z) * 0.5f - (gb.x + gb.z) * 0.5f;
                const float d1 = (bv.y + bv.w) * 0.5f - (gb.y + gb.w) * 0.5f;
                const float d2 = (bv.z - bv.x) - (gb.z - gb.x);
                const float d3 = (bv.w - bv.y) - (gb.w - gb.y);
                float ds[4] = {d0, d1, d2, d3};
#pragma unroll
                for (int q = 0; q < 4; ++q) {
                    float ax = fabsf(ds[q]);
                    loc += (ax < 1.0f) ? 0.5f * ax * ax : ax - 0.5f;
                }
            } else {
                const float nb = -log1pf(-p);
                int key = (int)(__float_as_uint(nb) >> 14) - (int)KOFF;
                key = key < 0 ? 0 : (key > NB - 1 ? NB - 1 : key);
                lk[ln++] = (unsigned short)key;
            }
        }
        if (ln) {
            const unsigned int slot = atomicAdd(&ncnt, (unsigned int)ln);
            for (int i = 0; i < ln; ++i) nk[slot + i] = lk[i];
        }
    }
    // block reduce np/pos/loc; barriers also fence nk/ncnt
    ru[t] = (unsigned int)np; rf[t] = pos; rf2[t] = loc;
    __syncthreads();
    // pad to even with sentinel so k_select can read u32 pairs (cnt odd =>
    // cnt <= 1023, so nk[cnt] is in bounds). Keys <= NB-1 < 0xFFFF.
    if (t == 0 && (ncnt & 1u)) nk[ncnt] = 0xFFFFu;
    for (int w = 128; w > 0; w >>= 1) {
        if (t < w) { ru[t] += ru[t + w]; rf[t] += rf[t + w]; rf2[t] += rf2[t + w]; }
        __syncthreads();
    }
    if (t == 0) {
        g_npart[b * NSEG + seg] = (int)ru[0];
        g_spart[(b * NSEG + seg) * 2 + 0] = rf[0];
        g_spart[(b * NSEG + seg) * 2 + 1] = rf2[0];
        g_ncnt[b * NSEG + seg] = (int)ncnt;
    }
    // coalesced u32 writeout of the compact keys (ceil(cnt/2) words)
    const unsigned int cw = (ncnt + 1u) >> 1;
    const unsigned int* nk32 = (const unsigned int*)nk;
    unsigned int* outk = (unsigned int*)(g_nkey + ((size_t)b * NSEG + seg) * SEGA);
    for (unsigned int j = t; j < cw; j += 256) outk[j] = nk32[j];
}

// ---------------------------------------------------------------------------
// Kernel 3: per-image hist build + hard-negative top-k + final combine.
// grid B, block 1024.
// R9 post-mortem: the hist build looped segments SERIALLY (64 dependent
// global round-trips, half the lanes idle) ~= 19us. R10: FLATTENED -- thread
// t walks flat word index w over the fixed 64 x 512-word layout
// (s = w>>9, j = w&511; skip j >= cw[s]): 32 independent coalesced
// iterations, loads pipelined. LDS u32 hist atomicAdd (hot bin ~23).
// Cross-block handoff: __threadfence + done counter; 16th block agent-scope
// loads and writes the dual-bf16-encoded output.
__global__ void __launch_bounds__(1024) k_select(unsigned int* __restrict__ out) {
    __shared__ unsigned int hist[NB];         // 32 KB
    __shared__ unsigned int ru[1024];
    __shared__ unsigned int s2[32];
    __shared__ int scw[NSEG];                 // word counts per segment
    __shared__ float sh_pos, sh_loc;
    __shared__ int sh_np, sh_k, sh_bsel;
    __shared__ unsigned int sh_take;
    __shared__ float rf[1024];

    const int b = blockIdx.x, t = threadIdx.x;
    for (int j = t; j < NB; j += 1024) hist[j] = 0u;
    if (t < NSEG) scw[t] = (g_ncnt[b * NSEG + t] + 1) >> 1;
    if (t < 64) {                             // wave-parallel seg-partial fold
        int np = g_npart[b * NSEG + t];
        float pos = g_spart[(b * NSEG + t) * 2 + 0];
        float loc = g_spart[(b * NSEG + t) * 2 + 1];
#pragma unroll
        for (int off = 32; off > 0; off >>= 1) {
            np  += __shfl_xor(np,  off, 64);
            pos += __shfl_xor(pos, off, 64);
            loc += __shfl_xor(loc, off, 64);
        }
        if (t == 0) { sh_np = np; sh_pos = pos; sh_loc = loc; }
    }
    __syncthreads();
    // flattened histogram of the compact keys (order-invariant -> bit-exact)
    {
        const unsigned int* kbase =
            (const unsigned int*)(g_nkey + (size_t)b * NSEG * SEGA);
#pragma unroll 4
        for (int w = t; w < NSEG * (SEGA / 2); w += 1024) {
            const int s = w >> 9;             // SEGA/2 = 512 u32 words/segment
            const int j = w & 511;
            if (j < scw[s]) {
                const unsigned int v = kbase[w];
                atomicAdd(&hist[v & 0xFFFFu], 1u);           // lo always valid
                const unsigned int k1 = v >> 16;
                if (k1 != 0xFFFFu) atomicAdd(&hist[k1], 1u); // hi unless pad
            }
        }
    }
    __syncthreads();
    const int np_tot = sh_np;

    // descending chunk counts: thread t covers bins NB-1-8t .. NB-8-8t
    unsigned int c = 0;
    const int hi = NB - 1 - t * 8;
#pragma unroll
    for (int j = 0; j < 8; ++j) c += hist[hi - j];
    ru[t] = c;
    __syncthreads();
    if (t < 32) {
        unsigned int x = 0;
#pragma unroll
        for (int j = 0; j < 32; ++j) x += ru[t * 32 + j];
        s2[t] = x;
    }
    __syncthreads();
    if (t == 0) {
        int k = 3 * np_tot;
        const int maxneg = AA - np_tot;
        if (k > maxneg) k = maxneg;
        sh_k = k;
        int bsel = NB;            // NB => nothing selected
        unsigned int take = 0;
        if (k > 0) {
            unsigned int cum = 0;
            int u = 0;
            while (u < 31 && cum + s2[u] < (unsigned int)k) { cum += s2[u]; ++u; }
            int cc = u * 32;
            while (cc < 1023 && cum + ru[cc] < (unsigned int)k) { cum += ru[cc]; ++cc; }
            const int h2 = NB - 1 - cc * 8;
            int j = 0;
            while (j < 7 && cum + hist[h2 - j] < (unsigned int)k) { cum += hist[h2 - j]; ++j; }
            bsel = h2 - j;
            take = (unsigned int)k - cum;
        }
        sh_bsel = bsel; sh_take = take;
    }
    __syncthreads();
    const int bsel = sh_bsel;
    float negp = 0.0f;
    for (int j = t; j < NB; j += 1024)
        if (j > bsel) { unsigned int cnt = hist[j]; if (cnt) negp += (float)cnt * midval(j); }
    rf[t] = negp;
    __syncthreads();
    for (int w = 512; w > 0; w >>= 1) {
        if (t < w) rf[t] += rf[t + w];
        __syncthreads();
    }
    if (t == 0) {
        float neg = 0.0f;
        if (sh_k > 0) neg = rf[0] + (float)sh_take * midval(bsel < NB ? bsel : 0);
        g_loc[b] = sh_loc; g_pos[b] = sh_pos; g_neg[b] = neg;
        g_npos[b] = np_tot; g_nneg[b] = sh_k;

        __threadfence();                        // publish before counting in
        const int old = atomicAdd(donep(), 1);
        if (old == BB - 1) {                    // last image: final combine
            __threadfence();
            float loc = 0.0f, conf = 0.0f;
            int tot = 0;
            for (int bb = 0; bb < BB; ++bb) {
                const float lv = __hip_atomic_load(&g_loc[bb],  __ATOMIC_RELAXED, __HIP_MEMORY_SCOPE_AGENT);
                const float pv = __hip_atomic_load(&g_pos[bb],  __ATOMIC_RELAXED, __HIP_MEMORY_SCOPE_AGENT);
                const float nv = __hip_atomic_load(&g_neg[bb],  __ATOMIC_RELAXED, __HIP_MEMORY_SCOPE_AGENT);
                const int   np = __hip_atomic_load(&g_npos[bb], __ATOMIC_RELAXED, __HIP_MEMORY_SCOPE_AGENT);
                const int   nn = __hip_atomic_load(&g_nneg[bb], __ATOMIC_RELAXED, __HIP_MEMORY_SCOPE_AGENT);
                loc += lv;
                conf += pv / (float)(np > 1 ? np : 1) +
                        nv / (float)(nn > 1 ? nn : 1);
                tot += np;
            }
            const float total = loc / (float)(tot > 1 ? tot : 1) + conf / (float)BB;
            const unsigned int u = __float_as_uint(total);
            const unsigned int r = 0x7FFFu + ((u >> 16) & 1u);
            const unsigned int bf = (u + r) >> 16;      // bf16(total), RNE
            out[0] = (bf << 16) | bf;
        }
    }
}

extern "C" void kernel_launch(void* const* d_in, const int* in_sizes, int n_in,
                              void* d_out, int out_size, void* d_ws, size_t ws_size,
                              hipStream_t stream) {
    const float4* bbox    = (const float4*)d_in[0];
    const float*  conf    = (const float*)d_in[1];
    const float4* anchors = (const float4*)d_in[2];
    const float4* gts     = (const float4*)d_in[3];

    static unsigned int* dynp = nullptr;       // cached symbol address
    if (!dynp) hipGetSymbolAddress((void**)&dynp, HIP_SYMBOL(g_dyn));
    hipMemsetAsync(dynp, 0, sizeof(unsigned int) * DYN_U32, stream);

    k_matchforce<<<dim3(MBLK, BB), 256, 0, stream>>>(anchors, gts);
    k_stats<<<dim3(NSEG, BB), 256, 0, stream>>>(bbox, conf, gts);
    k_select<<<BB, 1024, 0, stream>>>((unsigned int*)d_out);
}